// Round 8
// baseline (107.525 us; speedup 1.0000x reference)
//
#include <hip/hip_runtime.h>
#include <hip/hip_bf16.h>

#define D 128          // D_IN == D_OUT
#define K2 256         // 2*D (concat width)
#define NT 64          // nodes per block (16 per wave)
#define NTHREADS 256
#define AGM_LD 136     // aggM row stride (bf16) -> 272B: bank-clean b64/b128
#define WT_LD 68       // wtT row stride (bf16) -> 136B: bank-clean b64/b128
#define YT_LD 129      // ytile row stride (f32) -> 516B

typedef __attribute__((ext_vector_type(8))) short bf16x8;  // MFMA A/B frag
typedef __attribute__((ext_vector_type(4))) float f32x4;   // MFMA C/D frag
typedef __attribute__((ext_vector_type(2))) float f32x2;

static __device__ __forceinline__ unsigned short f2bf(float f) {
    __hip_bfloat16 h = __float2bfloat16(f);   // RNE
    return *reinterpret_cast<unsigned short*>(&h);
}

// ---------------- fp8 e4m3 (OCP) encode/decode helpers ----------------
static __device__ __forceinline__ unsigned int f2q_manual(float f) {
    f = fminf(fmaxf(f, -448.f), 448.f);
    unsigned int u = __float_as_uint(f * 0x1.0p-120f);
    const unsigned int lsb = (u >> 20) & 1u;
    u += 0x7ffffu + lsb;
    return ((u >> 24) & 0x80u) | ((u >> 20) & 0x7fu);
}
static __device__ __forceinline__ float q2f_manual(unsigned int b) {
    const unsigned int bits = ((b & 0x80u) << 24) | ((b & 0x7fu) << 20);
    return __uint_as_float(bits) * 0x1.0p+120f;
}
static __device__ __forceinline__ unsigned int pack_fp8x4(float4 v) {
#if __has_builtin(__builtin_amdgcn_cvt_pk_fp8_f32)
    int lo = __builtin_amdgcn_cvt_pk_fp8_f32(v.x, v.y, 0, false);
    int q  = __builtin_amdgcn_cvt_pk_fp8_f32(v.z, v.w, lo, true);
    return (unsigned int)q;
#else
    return f2q_manual(v.x) | (f2q_manual(v.y) << 8) |
           (f2q_manual(v.z) << 16) | (f2q_manual(v.w) << 24);
#endif
}
static __device__ __forceinline__ f32x2 unpack_fp8_lo(unsigned int v) {
#if __has_builtin(__builtin_amdgcn_cvt_pk_f32_fp8)
    return __builtin_amdgcn_cvt_pk_f32_fp8((int)v, false);
#else
    f32x2 r; r[0] = q2f_manual(v & 0xffu); r[1] = q2f_manual((v >> 8) & 0xffu); return r;
#endif
}
static __device__ __forceinline__ f32x2 unpack_fp8_hi(unsigned int v) {
#if __has_builtin(__builtin_amdgcn_cvt_pk_f32_fp8)
    return __builtin_amdgcn_cvt_pk_f32_fp8((int)v, true);
#else
    f32x2 r; r[0] = q2f_manual((v >> 16) & 0xffu); r[1] = q2f_manual((v >> 24) & 0xffu); return r;
#endif
}

// ------ Kernel A: x -> fp8 table (all rows) + bf16 self rows + bf16 W ------
__global__ __launch_bounds__(256)
void convert_all(const float* __restrict__ x, const float* __restrict__ W,
                 unsigned int* __restrict__ xq4,   // 4 fp8 per uint
                 uint2* __restrict__ xbs4,         // 4 bf16 per uint2 (self rows)
                 uint2* __restrict__ wb4,          // 4 bf16 per uint2
                 long n4x, long n4s, long n4w)
{
    const long gid = (long)blockIdx.x * blockDim.x + threadIdx.x;
    const long stride = (long)gridDim.x * blockDim.x;
    for (long t = gid; t < n4x; t += stride) {
        const float4 v = reinterpret_cast<const float4*>(x)[t];
        xq4[t] = pack_fp8x4(v);
        if (t < n4s) {
            uint2 p;
            p.x = (unsigned int)f2bf(v.x) | ((unsigned int)f2bf(v.y) << 16);
            p.y = (unsigned int)f2bf(v.z) | ((unsigned int)f2bf(v.w) << 16);
            xbs4[t] = p;
        }
    }
    for (long t = gid; t < n4w; t += stride) {
        const float4 v = reinterpret_cast<const float4*>(W)[t];
        uint2 p;
        p.x = (unsigned int)f2bf(v.x) | ((unsigned int)f2bf(v.y) << 16);
        p.y = (unsigned int)f2bf(v.z) | ((unsigned int)f2bf(v.w) << 16);
        wb4[t] = p;
    }
}

// ---- Kernel B: fp8 gather (8B/lane, quad-split wave) + MFMA GEMM +
//      LDS-transposed full-line epilogue ----
__global__ __launch_bounds__(NTHREADS, 4)
void sage_fp8c(const unsigned char* __restrict__ xq,
               const unsigned short* __restrict__ xbs,
               const unsigned short* __restrict__ wb,
               const int* __restrict__ rp,
               const int* __restrict__ ci,
               const float* __restrict__ lb,
               const float* __restrict__ bb,
               float* __restrict__ y,
               int n_out)
{
    // Union: phase1/2 use aggM(17408B)+wtT(17408B); epilogue reuses as ytile(33024B)
    __shared__ __align__(16) unsigned char smraw[34816];
    auto aggM  = reinterpret_cast<unsigned short (*)[AGM_LD]>(smraw);          // [64][136]
    auto wtT   = reinterpret_cast<unsigned short (*)[WT_LD]>(smraw + 17408);   // [128][68]
    auto ytile = reinterpret_cast<float (*)[YT_LD]>(smraw);                    // [64][129]
    __shared__ int rpls[NT + 1];
    __shared__ int cils[NT * 16];

    const int tid   = threadIdx.x;
    const int wave  = tid >> 6;
    const int lane  = tid & 63;
    const int node0 = blockIdx.x * NT;
    const int nt_act = min(NT, n_out - node0);

    if (tid <= nt_act) rpls[tid] = rp[node0 + tid];
    __syncthreads();
    const int e_base = rpls[0];
    const int e_cnt  = rpls[nt_act] - e_base;
    const bool fits  = (e_cnt <= NT * 16);
    if (fits) {
        for (int i = tid; i < e_cnt; i += NTHREADS) cils[i] = ci[e_base + i];
    }
    __syncthreads();

    // ---- Phase 1: gather. Quad-split: nsel = lane>>4 picks node of quad,
    //      each lane owns 8 dims (8 fp8 bytes) -> 16 8B-loads per quad. ----
    const int nsel = lane >> 4;                  // 0..3
    const int dl   = (lane & 15) * 8;            // dim base (0,8,...,120)

    for (int p = 0; p < 4; ++p) {
        const int n0 = wave * 16 + p * 4;
        if (n0 >= nt_act) break;
        const int nrem   = nt_act - n0;
        const int my_n   = n0 + nsel;
        const bool active = (nsel < nrem);

        int my_s = 0, my_d = 0;
        if (active) {
            my_s = rpls[my_n] - e_base;
            my_d = rpls[my_n + 1] - e_base - my_s;
        }

        float a0=0.f,a1=0.f,a2=0.f,a3=0.f,a4=0.f,a5=0.f,a6=0.f,a7=0.f;
        const bool fast = fits && (nrem >= 4) && __all(my_d == 16);
        if (fast) {
            int idx[16];
            #pragma unroll
            for (int u = 0; u < 16; ++u) idx[u] = cils[my_s + u];
            #pragma unroll
            for (int u = 0; u < 16; ++u) {
                const uint2 v = *reinterpret_cast<const uint2*>(
                    &xq[(size_t)idx[u] * D + dl]);
                const f32x2 e0 = unpack_fp8_lo(v.x);
                const f32x2 e1 = unpack_fp8_hi(v.x);
                const f32x2 e2 = unpack_fp8_lo(v.y);
                const f32x2 e3 = unpack_fp8_hi(v.y);
                a0 += e0[0]; a1 += e0[1]; a2 += e1[0]; a3 += e1[1];
                a4 += e2[0]; a5 += e2[1]; a6 += e3[0]; a7 += e3[1];
            }
        } else if (active) {
            for (int u = 0; u < my_d; ++u) {
                const int c = fits ? cils[my_s + u] : ci[e_base + my_s + u];
                const uint2 v = *reinterpret_cast<const uint2*>(
                    &xq[(size_t)c * D + dl]);
                const f32x2 e0 = unpack_fp8_lo(v.x);
                const f32x2 e1 = unpack_fp8_hi(v.x);
                const f32x2 e2 = unpack_fp8_lo(v.y);
                const f32x2 e3 = unpack_fp8_hi(v.y);
                a0 += e0[0]; a1 += e0[1]; a2 += e1[0]; a3 += e1[1];
                a4 += e2[0]; a5 += e2[1]; a6 += e3[0]; a7 += e3[1];
            }
        }
        if (active) {
            const float inv = 1.0f / (float)max(my_d, 1);
            uint4 pk;
            pk.x = (unsigned int)f2bf(a0 * inv) | ((unsigned int)f2bf(a1 * inv) << 16);
            pk.y = (unsigned int)f2bf(a2 * inv) | ((unsigned int)f2bf(a3 * inv) << 16);
            pk.z = (unsigned int)f2bf(a4 * inv) | ((unsigned int)f2bf(a5 * inv) << 16);
            pk.w = (unsigned int)f2bf(a6 * inv) | ((unsigned int)f2bf(a7 * inv) << 16);
            *reinterpret_cast<uint4*>(&aggM[my_n][dl]) = pk;   // 16B, bank-spread
        }
    }
    // (first __syncthreads in GEMM loop publishes aggM)

    // ---- Phase 2: MFMA GEMM. Per wave: M=16 x N=128, K=256 in 4 chunks ----
    const int n15 = lane & 15;
    const int g   = lane >> 4;

    // Hoist self A-frags (k=0..127) from the bf16 self table (L2/L3).
    const int arow = min(node0 + wave * 16 + n15, n_out - 1);
    bf16x8 aself[4];
    #pragma unroll
    for (int c = 0; c < 4; ++c)
        aself[c] = *reinterpret_cast<const bf16x8*>(
            &xbs[(size_t)arow * D + c * 32 + g * 8]);

    f32x4 acc[8];
    #pragma unroll
    for (int f = 0; f < 8; ++f) acc[f] = (f32x4){0.f, 0.f, 0.f, 0.f};

    #pragma unroll
    for (int ch = 0; ch < 4; ++ch) {             // k0 = ch*64
        const int k0 = ch * 64;
        #pragma unroll
        for (int j = 0; j < 8; ++j) {
            const int flat = j * 256 + tid;      // 2048 uint2
            const int o    = flat >> 4;          // 0..127
            const int q    = flat & 15;          // 0..15
            *reinterpret_cast<uint2*>(&wtT[o][q * 4]) =
                *reinterpret_cast<const uint2*>(&wb[(size_t)o * K2 + k0 + q * 4]);
        }
        __syncthreads();

        #pragma unroll
        for (int sub = 0; sub < 2; ++sub) {      // kk = k0 + sub*32
            const int kk = k0 + sub * 32;
            const bf16x8 a = (kk < 128)
                ? aself[ch * 2 + sub]
                : *reinterpret_cast<const bf16x8*>(
                      &aggM[wave * 16 + n15][(kk - 128) + g * 8]);
            #pragma unroll
            for (int f = 0; f < 8; ++f) {
                const bf16x8 b = *reinterpret_cast<const bf16x8*>(
                    &wtT[f * 16 + n15][sub * 32 + g * 8]);
                acc[f] = __builtin_amdgcn_mfma_f32_16x16x32_bf16(a, b, acc[f], 0, 0, 0);
            }
        }
        __syncthreads();   // after final chunk: aggM/wtT dead -> ytile alias safe
    }

    // ---- Epilogue: transpose via wave-private ytile rows, full-line stores ----
    // acc[f][r] holds (local row = g*4+r, col = f*16+n15) of this wave's 16x128 tile.
    #pragma unroll
    for (int f = 0; f < 8; ++f) {
        #pragma unroll
        for (int r = 0; r < 4; ++r)
            ytile[wave * 16 + g * 4 + r][f * 16 + n15] = acc[f][r];
    }
    // (wave-private rows: no barrier needed; compiler orders ds_write->ds_read)

    const int c4 = (lane & 31) * 4;
    const float4 blv = *reinterpret_cast<const float4*>(&lb[c4]);
    const float4 bbv = *reinterpret_cast<const float4*>(&bb[c4]);
    const float bx = blv.x + bbv.x, by = blv.y + bbv.y;
    const float bz = blv.z + bbv.z, bw = blv.w + bbv.w;

    #pragma unroll
    for (int pass = 0; pass < 8; ++pass) {
        const int rl  = pass * 2 + (lane >> 5);      // local row 0..15
        const int row = node0 + wave * 16 + rl;
        float4 v = *reinterpret_cast<const float4*>(&ytile[wave * 16 + rl][c4]);
        v.x += bx; v.y += by; v.z += bz; v.w += bw;
        if (row < n_out)
            *reinterpret_cast<float4*>(&y[(size_t)row * D + c4]) = v;
    }
}

// --------- Fallback (fp32 gather, barriered) if ws too small ---------
#define AGG_LDF 264
__global__ __launch_bounds__(NTHREADS, 3)
void sage_fused3(const float* __restrict__ x,
                 const int* __restrict__ rp,
                 const int* __restrict__ ci,
                 const float* __restrict__ W,
                 const float* __restrict__ lb,
                 const float* __restrict__ bb,
                 float* __restrict__ y,
                 int n_out)
{
    __shared__ unsigned short aggB[NT][AGG_LDF];
    __shared__ unsigned short wtTF[D][32];
    __shared__ int rplsF[NT + 1];
    __shared__ int cilsF[NT * 16];

    const int tid   = threadIdx.x;
    const int wave  = tid >> 6;
    const int lane  = tid & 63;
    const int node0 = blockIdx.x * NT;
    const int nt_act = min(NT, n_out - node0);

    if (tid <= nt_act) rplsF[tid] = rp[node0 + tid];
    __syncthreads();
    const int e_base = rplsF[0];
    const int e_cnt  = rplsF[nt_act] - e_base;
    const bool fits  = (e_cnt <= NT * 16);
    if (fits) {
        for (int i = tid; i < e_cnt; i += NTHREADS) cilsF[i] = ci[e_base + i];
    }
    __syncthreads();

    for (int t = 0; t < 16; ++t) {
        const int nn = wave * 16 + t;
        if (nn >= nt_act) break;
        const int node = node0 + nn;
        const float2 self =
            *reinterpret_cast<const float2*>(&x[(size_t)node * D + lane * 2]);
        const int s  = rplsF[nn] - e_base;
        const int dg = rplsF[nn + 1] - e_base - s;
        float ax = 0.f, ay = 0.f;
        for (int u = 0; u < dg; ++u) {
            const int c = fits ? cilsF[s + u] : ci[e_base + s + u];
            const float2 v = *reinterpret_cast<const float2*>(
                &x[(size_t)c * D + lane * 2]);
            ax += v.x; ay += v.y;
        }
        const float inv = 1.0f / (float)max(dg, 1);
        *reinterpret_cast<unsigned int*>(&aggB[nn][lane * 2]) =
            (unsigned int)f2bf(self.x) | ((unsigned int)f2bf(self.y) << 16);
        *reinterpret_cast<unsigned int*>(&aggB[nn][D + lane * 2]) =
            (unsigned int)f2bf(ax * inv) | ((unsigned int)f2bf(ay * inv) << 16);
    }

    const int n15 = lane & 15;
    const int g   = lane >> 4;
    f32x4 acc[8];
    #pragma unroll
    for (int f = 0; f < 8; ++f) acc[f] = (f32x4){0.f, 0.f, 0.f, 0.f};

    for (int k0 = 0; k0 < K2; k0 += 32) {
        #pragma unroll
        for (int j = 0; j < 4; ++j) {
            const int idx = j * 256 + tid;
            const int o   = idx >> 3;
            const int c   = idx & 7;
            const float4 w = *reinterpret_cast<const float4*>(
                &W[(size_t)o * K2 + k0 + c * 4]);
            const unsigned int lo = (unsigned int)f2bf(w.x) | ((unsigned int)f2bf(w.y) << 16);
            const unsigned int hi = (unsigned int)f2bf(w.z) | ((unsigned int)f2bf(w.w) << 16);
            *reinterpret_cast<uint2*>(&wtTF[o][c * 4]) = make_uint2(lo, hi);
        }
        __syncthreads();
        const bf16x8 a = *reinterpret_cast<const bf16x8*>(
            &aggB[wave * 16 + n15][k0 + g * 8]);
        #pragma unroll
        for (int f = 0; f < 8; ++f) {
            const bf16x8 b = *reinterpret_cast<const bf16x8*>(&wtTF[f * 16 + n15][g * 8]);
            acc[f] = __builtin_amdgcn_mfma_f32_16x16x32_bf16(a, b, acc[f], 0, 0, 0);
        }
        __syncthreads();
    }

    const int mbase = node0 + wave * 16 + g * 4;
    #pragma unroll
    for (int f = 0; f < 8; ++f) {
        const int col  = f * 16 + n15;
        const float bs = lb[col] + bb[col];
        #pragma unroll
        for (int r = 0; r < 4; ++r) {
            const int row = mbase + r;
            if (row < n_out)
                y[(size_t)row * D + col] = acc[f][r] + bs;
        }
    }
}

extern "C" void kernel_launch(void* const* d_in, const int* in_sizes, int n_in,
                              void* d_out, int out_size, void* d_ws, size_t ws_size,
                              hipStream_t stream)
{
    const float* x  = (const float*)d_in[0];
    const int*   rp = (const int*)d_in[1];
    const int*   ci = (const int*)d_in[2];
    // d_in[3] = sample_count (scalar) — degree comes from row_ptr
    const float* W  = (const float*)d_in[4];
    const float* lb = (const float*)d_in[5];
    const float* bb = (const float*)d_in[6];
    float* y = (float*)d_out;

    const int n_out = in_sizes[1] - 1;
    const int grid  = (n_out + NT - 1) / NT;

    const size_t n_x = (size_t)in_sizes[0];
    const size_t n_w = (size_t)in_sizes[4];
    const size_t xq_bytes  = n_x;                         // fp8: 1 B/elem
    const size_t xbs_bytes = (size_t)n_out * D * 2;       // bf16 self rows
    const size_t wb_bytes  = n_w * 2;
    const size_t need = xq_bytes + xbs_bytes + wb_bytes;

    if (ws_size >= need) {
        unsigned char*  xq  = (unsigned char*)d_ws;
        unsigned short* xbs = (unsigned short*)((char*)d_ws + xq_bytes);
        unsigned short* wb  = (unsigned short*)((char*)d_ws + xq_bytes + xbs_bytes);
        hipLaunchKernelGGL(convert_all, dim3(2048), dim3(256), 0, stream,
                           x, W, (unsigned int*)xq, (uint2*)xbs, (uint2*)wb,
                           (long)(n_x >> 2), (long)(((size_t)n_out * D) >> 2),
                           (long)(n_w >> 2));
        hipLaunchKernelGGL(sage_fp8c, dim3(grid), dim3(NTHREADS), 0, stream,
                           xq, xbs, wb, rp, ci, lb, bb, y, n_out);
    } else {
        hipLaunchKernelGGL(sage_fused3, dim3(grid), dim3(NTHREADS), 0, stream,
                           x, rp, ci, W, lb, bb, y, n_out);
    }
}

// Round 10
// 81.021 us; speedup vs baseline: 1.3271x; 1.3271x over previous
//
#include <hip/hip_runtime.h>
#include <hip/hip_bf16.h>

#define D 128          // D_IN == D_OUT
#define K2 256         // 2*D (concat width)
#define NT 64          // nodes per block (16 per wave)
#define NTHREADS 256
#define AGM_LD 136     // aggM row stride (bf16) -> 272B: bank-clean b64/b128
#define WT_LD 68       // wtT row stride (bf16) -> 136B: bank-clean b64/b128

typedef __attribute__((ext_vector_type(8))) short bf16x8;  // MFMA A/B frag
typedef __attribute__((ext_vector_type(4))) float f32x4;   // MFMA C/D frag
typedef __attribute__((ext_vector_type(2))) float f32x2;
typedef __attribute__((ext_vector_type(4))) float f32x4v;  // for nontemporal ld

static __device__ __forceinline__ unsigned short f2bf(float f) {
    __hip_bfloat16 h = __float2bfloat16(f);   // RNE
    return *reinterpret_cast<unsigned short*>(&h);
}

// ---------------- fp8 e4m3 (OCP) encode/decode helpers ----------------
static __device__ __forceinline__ unsigned int f2q_manual(float f) {
    f = fminf(fmaxf(f, -448.f), 448.f);
    unsigned int u = __float_as_uint(f * 0x1.0p-120f);
    const unsigned int lsb = (u >> 20) & 1u;
    u += 0x7ffffu + lsb;
    return ((u >> 24) & 0x80u) | ((u >> 20) & 0x7fu);
}
static __device__ __forceinline__ float q2f_manual(unsigned int b) {
    const unsigned int bits = ((b & 0x80u) << 24) | ((b & 0x7fu) << 20);
    return __uint_as_float(bits) * 0x1.0p+120f;
}
static __device__ __forceinline__ unsigned int pack_fp8x4(f32x4v v) {
#if __has_builtin(__builtin_amdgcn_cvt_pk_fp8_f32)
    int lo = __builtin_amdgcn_cvt_pk_fp8_f32(v.x, v.y, 0, false);
    int q  = __builtin_amdgcn_cvt_pk_fp8_f32(v.z, v.w, lo, true);
    return (unsigned int)q;
#else
    return f2q_manual(v.x) | (f2q_manual(v.y) << 8) |
           (f2q_manual(v.z) << 16) | (f2q_manual(v.w) << 24);
#endif
}
static __device__ __forceinline__ f32x2 unpack_fp8_lo(unsigned int v) {
#if __has_builtin(__builtin_amdgcn_cvt_pk_f32_fp8)
    return __builtin_amdgcn_cvt_pk_f32_fp8((int)v, false);
#else
    f32x2 r; r[0] = q2f_manual(v & 0xffu); r[1] = q2f_manual((v >> 8) & 0xffu); return r;
#endif
}
static __device__ __forceinline__ f32x2 unpack_fp8_hi(unsigned int v) {
#if __has_builtin(__builtin_amdgcn_cvt_pk_f32_fp8)
    return __builtin_amdgcn_cvt_pk_f32_fp8((int)v, true);
#else
    f32x2 r; r[0] = q2f_manual((v >> 16) & 0xffu); r[1] = q2f_manual((v >> 24) & 0xffu); return r;
#endif
}

// ------ Kernel A: x -> fp8 table (all rows) + bf16 self rows + bf16 W ------
// x/W reads are single-use -> nontemporal (don't pollute L3 ahead of gather).
__global__ __launch_bounds__(256)
void convert_all(const float* __restrict__ x, const float* __restrict__ W,
                 unsigned int* __restrict__ xq4,   // 4 fp8 per uint
                 uint2* __restrict__ xbs4,         // 4 bf16 per uint2 (self rows)
                 uint2* __restrict__ wb4,          // 4 bf16 per uint2
                 long n4x, long n4s, long n4w)
{
    const long gid = (long)blockIdx.x * blockDim.x + threadIdx.x;
    const long stride = (long)gridDim.x * blockDim.x;
    for (long t = gid; t < n4x; t += stride) {
        const f32x4v v = __builtin_nontemporal_load(
            &reinterpret_cast<const f32x4v*>(x)[t]);
        xq4[t] = pack_fp8x4(v);
        if (t < n4s) {
            uint2 p;
            p.x = (unsigned int)f2bf(v.x) | ((unsigned int)f2bf(v.y) << 16);
            p.y = (unsigned int)f2bf(v.z) | ((unsigned int)f2bf(v.w) << 16);
            xbs4[t] = p;
        }
    }
    for (long t = gid; t < n4w; t += stride) {
        const f32x4v v = __builtin_nontemporal_load(
            &reinterpret_cast<const f32x4v*>(W)[t]);
        uint2 p;
        p.x = (unsigned int)f2bf(v.x) | ((unsigned int)f2bf(v.y) << 16);
        p.y = (unsigned int)f2bf(v.z) | ((unsigned int)f2bf(v.w) << 16);
        wb4[t] = p;
    }
}

// ---- Kernel B: fp8 gather (4B/lane, half-wave node split) + MFMA GEMM ----
// R6 structure (57.7us) + pk-add accumulators + nontemporal y stores.
__global__ __launch_bounds__(NTHREADS, 4)
void sage_fp8b(const unsigned char* __restrict__ xq,
               const unsigned short* __restrict__ xbs,
               const unsigned short* __restrict__ wb,
               const int* __restrict__ rp,
               const int* __restrict__ ci,
               const float* __restrict__ lb,
               const float* __restrict__ bb,
               float* __restrict__ y,
               int n_out)
{
    __shared__ unsigned short aggM[NT][AGM_LD];  // bf16 mean half only
    __shared__ unsigned short wtT[D][WT_LD];     // bf16 W chunk: wtT[o][k-k0]
    __shared__ int rpls[NT + 1];
    __shared__ int cils[NT * 16];

    const int tid   = threadIdx.x;
    const int wave  = tid >> 6;
    const int lane  = tid & 63;
    const int node0 = blockIdx.x * NT;
    const int nt_act = min(NT, n_out - node0);

    if (tid <= nt_act) rpls[tid] = rp[node0 + tid];
    __syncthreads();
    const int e_base = rpls[0];
    const int e_cnt  = rpls[nt_act] - e_base;
    const bool fits  = (e_cnt <= NT * 16);
    if (fits) {
        for (int i = tid; i < e_cnt; i += NTHREADS) cils[i] = ci[e_base + i];
    }
    __syncthreads();

    // ---- Phase 1: gather. Half-wave split: nsel = lane>>5 picks node of pair;
    //      each lane owns 4 dims (4 fp8 bytes) -> 16 4B-loads per pair. ----
    const int nsel = lane >> 5;
    const int dg4  = (lane & 31) * 4;            // dim base (0,4,...,124)

    for (int p = 0; p < 8; ++p) {
        const int n0 = wave * 16 + p * 2;
        if (n0 >= nt_act) break;
        const bool has1 = (n0 + 1 < nt_act);

        const int s0 = rpls[n0] - e_base;
        const int d0 = rpls[n0 + 1] - e_base - s0;
        int s1 = s0, d1 = d0;
        if (has1) { s1 = rpls[n0 + 1] - e_base; d1 = rpls[n0 + 2] - e_base - s1; }

        const int  my_n   = n0 + nsel;
        const int  my_s   = nsel ? s1 : s0;
        const int  my_d   = nsel ? d1 : d0;
        const bool active = (nsel == 0) || has1;

        f32x2 a01 = (f32x2){0.f, 0.f};
        f32x2 a23 = (f32x2){0.f, 0.f};
        if (fits && has1 && d0 == 16 && d1 == 16) {
            int idx[16];
            #pragma unroll
            for (int u = 0; u < 16; ++u) idx[u] = cils[my_s + u];
            #pragma unroll
            for (int u = 0; u < 16; ++u) {
                const unsigned int v = *reinterpret_cast<const unsigned int*>(
                    &xq[(size_t)idx[u] * D + dg4]);
                a01 += unpack_fp8_lo(v);         // v_pk_add_f32
                a23 += unpack_fp8_hi(v);
            }
        } else if (active) {
            for (int u = 0; u < my_d; ++u) {
                const int c = fits ? cils[my_s + u] : ci[e_base + my_s + u];
                const unsigned int v = *reinterpret_cast<const unsigned int*>(
                    &xq[(size_t)c * D + dg4]);
                a01 += unpack_fp8_lo(v);
                a23 += unpack_fp8_hi(v);
            }
        }
        if (active) {
            const float inv = 1.0f / (float)max(my_d, 1);
            uint2 pk;
            pk.x = (unsigned int)f2bf(a01[0] * inv) | ((unsigned int)f2bf(a01[1] * inv) << 16);
            pk.y = (unsigned int)f2bf(a23[0] * inv) | ((unsigned int)f2bf(a23[1] * inv) << 16);
            *reinterpret_cast<uint2*>(&aggM[my_n][dg4]) = pk;   // 8B, bank-clean
        }
    }
    // (first __syncthreads in GEMM loop publishes aggM)

    // ---- Phase 2: MFMA GEMM. Per wave: M=16 x N=128, K=256 in 4 chunks ----
    const int n15 = lane & 15;
    const int g   = lane >> 4;

    // Hoist self A-frags (k=0..127) from the bf16 self table (L2/L3).
    const int arow = min(node0 + wave * 16 + n15, n_out - 1);
    bf16x8 aself[4];
    #pragma unroll
    for (int c = 0; c < 4; ++c)
        aself[c] = *reinterpret_cast<const bf16x8*>(
            &xbs[(size_t)arow * D + c * 32 + g * 8]);

    f32x4 acc[8];
    #pragma unroll
    for (int f = 0; f < 8; ++f) acc[f] = (f32x4){0.f, 0.f, 0.f, 0.f};

    #pragma unroll
    for (int ch = 0; ch < 4; ++ch) {             // k0 = ch*64
        const int k0 = ch * 64;
        // Stage wtT[o][0..63] = wb[o][k0..k0+63]; uint2 per thread x8.
        #pragma unroll
        for (int j = 0; j < 8; ++j) {
            const int flat = j * 256 + tid;      // 2048 uint2
            const int o    = flat >> 4;          // 0..127
            const int q    = flat & 15;          // 0..15
            *reinterpret_cast<uint2*>(&wtT[o][q * 4]) =
                *reinterpret_cast<const uint2*>(&wb[(size_t)o * K2 + k0 + q * 4]);
        }
        __syncthreads();

        #pragma unroll
        for (int sub = 0; sub < 2; ++sub) {      // kk = k0 + sub*32
            const int kk = k0 + sub * 32;
            const bf16x8 a = (kk < 128)
                ? aself[ch * 2 + sub]
                : *reinterpret_cast<const bf16x8*>(
                      &aggM[wave * 16 + n15][(kk - 128) + g * 8]);
            #pragma unroll
            for (int f = 0; f < 8; ++f) {
                const bf16x8 b = *reinterpret_cast<const bf16x8*>(
                    &wtT[f * 16 + n15][sub * 32 + g * 8]);
                acc[f] = __builtin_amdgcn_mfma_f32_16x16x32_bf16(a, b, acc[f], 0, 0, 0);
            }
        }
        __syncthreads();
    }

    // ---- Epilogue: D layout col = lane&15, row = (lane>>4)*4 + reg ----
    // Nontemporal: y has no reuse; keep it out of L3 so gather tables stay hot.
    const int mbase = node0 + wave * 16 + g * 4;
    #pragma unroll
    for (int f = 0; f < 8; ++f) {
        const int col  = f * 16 + n15;
        const float bs = lb[col] + bb[col];
        #pragma unroll
        for (int r = 0; r < 4; ++r) {
            const int row = mbase + r;
            if (row < n_out)
                __builtin_nontemporal_store(acc[f][r] + bs, &y[(size_t)row * D + col]);
        }
    }
}

// --------- Fallback (fp32 gather, barriered) if ws too small ---------
#define AGG_LDF 264
__global__ __launch_bounds__(NTHREADS, 3)
void sage_fused3(const float* __restrict__ x,
                 const int* __restrict__ rp,
                 const int* __restrict__ ci,
                 const float* __restrict__ W,
                 const float* __restrict__ lb,
                 const float* __restrict__ bb,
                 float* __restrict__ y,
                 int n_out)
{
    __shared__ unsigned short aggB[NT][AGG_LDF];
    __shared__ unsigned short wtTF[D][32];
    __shared__ int rplsF[NT + 1];
    __shared__ int cilsF[NT * 16];

    const int tid   = threadIdx.x;
    const int wave  = tid >> 6;
    const int lane  = tid & 63;
    const int node0 = blockIdx.x * NT;
    const int nt_act = min(NT, n_out - node0);

    if (tid <= nt_act) rplsF[tid] = rp[node0 + tid];
    __syncthreads();
    const int e_base = rplsF[0];
    const int e_cnt  = rplsF[nt_act] - e_base;
    const bool fits  = (e_cnt <= NT * 16);
    if (fits) {
        for (int i = tid; i < e_cnt; i += NTHREADS) cilsF[i] = ci[e_base + i];
    }
    __syncthreads();

    for (int t = 0; t < 16; ++t) {
        const int nn = wave * 16 + t;
        if (nn >= nt_act) break;
        const int node = node0 + nn;
        const float2 self =
            *reinterpret_cast<const float2*>(&x[(size_t)node * D + lane * 2]);
        const int s  = rplsF[nn] - e_base;
        const int dg = rplsF[nn + 1] - e_base - s;
        float ax = 0.f, ay = 0.f;
        for (int u = 0; u < dg; ++u) {
            const int c = fits ? cilsF[s + u] : ci[e_base + s + u];
            const float2 v = *reinterpret_cast<const float2*>(
                &x[(size_t)c * D + lane * 2]);
            ax += v.x; ay += v.y;
        }
        const float inv = 1.0f / (float)max(dg, 1);
        *reinterpret_cast<unsigned int*>(&aggB[nn][lane * 2]) =
            (unsigned int)f2bf(self.x) | ((unsigned int)f2bf(self.y) << 16);
        *reinterpret_cast<unsigned int*>(&aggB[nn][D + lane * 2]) =
            (unsigned int)f2bf(ax * inv) | ((unsigned int)f2bf(ay * inv) << 16);
    }

    const int n15 = lane & 15;
    const int g   = lane >> 4;
    f32x4 acc[8];
    #pragma unroll
    for (int f = 0; f < 8; ++f) acc[f] = (f32x4){0.f, 0.f, 0.f, 0.f};

    for (int k0 = 0; k0 < K2; k0 += 32) {
        #pragma unroll
        for (int j = 0; j < 4; ++j) {
            const int idx = j * 256 + tid;
            const int o   = idx >> 3;
            const int c   = idx & 7;
            const float4 w = *reinterpret_cast<const float4*>(
                &W[(size_t)o * K2 + k0 + c * 4]);
            const unsigned int lo = (unsigned int)f2bf(w.x) | ((unsigned int)f2bf(w.y) << 16);
            const unsigned int hi = (unsigned int)f2bf(w.z) | ((unsigned int)f2bf(w.w) << 16);
            *reinterpret_cast<uint2*>(&wtTF[o][c * 4]) = make_uint2(lo, hi);
        }
        __syncthreads();
        const bf16x8 a = *reinterpret_cast<const bf16x8*>(
            &aggB[wave * 16 + n15][k0 + g * 8]);
        #pragma unroll
        for (int f = 0; f < 8; ++f) {
            const bf16x8 b = *reinterpret_cast<const bf16x8*>(&wtTF[f * 16 + n15][g * 8]);
            acc[f] = __builtin_amdgcn_mfma_f32_16x16x32_bf16(a, b, acc[f], 0, 0, 0);
        }
        __syncthreads();
    }

    const int mbase = node0 + wave * 16 + g * 4;
    #pragma unroll
    for (int f = 0; f < 8; ++f) {
        const int col  = f * 16 + n15;
        const float bs = lb[col] + bb[col];
        #pragma unroll
        for (int r = 0; r < 4; ++r) {
            const int row = mbase + r;
            if (row < n_out)
                y[(size_t)row * D + col] = acc[f][r] + bs;
        }
    }
}

extern "C" void kernel_launch(void* const* d_in, const int* in_sizes, int n_in,
                              void* d_out, int out_size, void* d_ws, size_t ws_size,
                              hipStream_t stream)
{
    const float* x  = (const float*)d_in[0];
    const int*   rp = (const int*)d_in[1];
    const int*   ci = (const int*)d_in[2];
    // d_in[3] = sample_count (scalar) — degree comes from row_ptr
    const float* W  = (const float*)d_in[4];
    const float* lb = (const float*)d_in[5];
    const float* bb = (const float*)d_in[6];
    float* y = (float*)d_out;

    const int n_out = in_sizes[1] - 1;
    const int grid  = (n_out + NT - 1) / NT;

    const size_t n_x = (size_t)in_sizes[0];
    const size_t n_w = (size_t)in_sizes[4];
    const size_t xq_bytes  = n_x;                         // fp8: 1 B/elem
    const size_t xbs_bytes = (size_t)n_out * D * 2;       // bf16 self rows
    const size_t wb_bytes  = n_w * 2;
    const size_t need = xq_bytes + xbs_bytes + wb_bytes;

    if (ws_size >= need) {
        unsigned char*  xq  = (unsigned char*)d_ws;
        unsigned short* xbs = (unsigned short*)((char*)d_ws + xq_bytes);
        unsigned short* wb  = (unsigned short*)((char*)d_ws + xq_bytes + xbs_bytes);
        hipLaunchKernelGGL(convert_all, dim3(2048), dim3(256), 0, stream,
                           x, W, (unsigned int*)xq, (uint2*)xbs, (uint2*)wb,
                           (long)(n_x >> 2), (long)(((size_t)n_out * D) >> 2),
                           (long)(n_w >> 2));
        hipLaunchKernelGGL(sage_fp8b, dim3(grid), dim3(NTHREADS), 0, stream,
                           xq, xbs, wb, rp, ci, lb, bb, y, n_out);
    } else {
        hipLaunchKernelGGL(sage_fused3, dim3(grid), dim3(NTHREADS), 0, stream,
                           x, rp, ci, W, lb, bb, y, n_out);
    }
}

// Round 11
// 75.266 us; speedup vs baseline: 1.4286x; 1.0765x over previous
//
#include <hip/hip_runtime.h>
#include <hip/hip_bf16.h>

#define D 128          // D_IN == D_OUT
#define K2 256         // 2*D (concat width)
#define NT 64          // nodes per block (8 per wave)
#define NTHREADS 512   // 8 waves
#define AGM_LD 136     // agg row stride (bf16) -> 272B: bank-clean b64/b128

typedef __attribute__((ext_vector_type(8))) short bf16x8;  // MFMA A/B frag
typedef __attribute__((ext_vector_type(4))) float f32x4;   // MFMA C/D frag
typedef __attribute__((ext_vector_type(2))) float f32x2;

static __device__ __forceinline__ unsigned short f2bf(float f) {
    __hip_bfloat16 h = __float2bfloat16(f);   // RNE
    return *reinterpret_cast<unsigned short*>(&h);
}

// ---------------- fp8 e4m3 (OCP) encode/decode helpers ----------------
static __device__ __forceinline__ unsigned int f2q_manual(float f) {
    f = fminf(fmaxf(f, -448.f), 448.f);
    unsigned int u = __float_as_uint(f * 0x1.0p-120f);
    const unsigned int lsb = (u >> 20) & 1u;
    u += 0x7ffffu + lsb;
    return ((u >> 24) & 0x80u) | ((u >> 20) & 0x7fu);
}
static __device__ __forceinline__ float q2f_manual(unsigned int b) {
    const unsigned int bits = ((b & 0x80u) << 24) | ((b & 0x7fu) << 20);
    return __uint_as_float(bits) * 0x1.0p+120f;
}
static __device__ __forceinline__ unsigned int pack_fp8x4(float4 v) {
#if __has_builtin(__builtin_amdgcn_cvt_pk_fp8_f32)
    int lo = __builtin_amdgcn_cvt_pk_fp8_f32(v.x, v.y, 0, false);
    int q  = __builtin_amdgcn_cvt_pk_fp8_f32(v.z, v.w, lo, true);
    return (unsigned int)q;
#else
    return f2q_manual(v.x) | (f2q_manual(v.y) << 8) |
           (f2q_manual(v.z) << 16) | (f2q_manual(v.w) << 24);
#endif
}
static __device__ __forceinline__ f32x2 unpack_fp8_lo(unsigned int v) {
#if __has_builtin(__builtin_amdgcn_cvt_pk_f32_fp8)
    return __builtin_amdgcn_cvt_pk_f32_fp8((int)v, false);
#else
    f32x2 r; r[0] = q2f_manual(v & 0xffu); r[1] = q2f_manual((v >> 8) & 0xffu); return r;
#endif
}
static __device__ __forceinline__ f32x2 unpack_fp8_hi(unsigned int v) {
#if __has_builtin(__builtin_amdgcn_cvt_pk_f32_fp8)
    return __builtin_amdgcn_cvt_pk_f32_fp8((int)v, true);
#else
    f32x2 r; r[0] = q2f_manual((v >> 16) & 0xffu); r[1] = q2f_manual((v >> 24) & 0xffu); return r;
#endif
}

// ------ Kernel A: x -> fp8 table (all rows) + bf16 self rows + bf16 W ------
__global__ __launch_bounds__(256)
void convert_all(const float* __restrict__ x, const float* __restrict__ W,
                 unsigned int* __restrict__ xq4,   // 4 fp8 per uint
                 uint2* __restrict__ xbs4,         // 4 bf16 per uint2 (self rows)
                 uint2* __restrict__ wb4,          // 4 bf16 per uint2
                 long n4x, long n4s, long n4w)
{
    const long gid = (long)blockIdx.x * blockDim.x + threadIdx.x;
    const long stride = (long)gridDim.x * blockDim.x;
    for (long t = gid; t < n4x; t += stride) {
        const float4 v = reinterpret_cast<const float4*>(x)[t];
        xq4[t] = pack_fp8x4(v);
        if (t < n4s) {
            uint2 p;
            p.x = (unsigned int)f2bf(v.x) | ((unsigned int)f2bf(v.y) << 16);
            p.y = (unsigned int)f2bf(v.z) | ((unsigned int)f2bf(v.w) << 16);
            xbs4[t] = p;
        }
    }
    for (long t = gid; t < n4w; t += stride) {
        const float4 v = reinterpret_cast<const float4*>(W)[t];
        uint2 p;
        p.x = (unsigned int)f2bf(v.x) | ((unsigned int)f2bf(v.y) << 16);
        p.y = (unsigned int)f2bf(v.z) | ((unsigned int)f2bf(v.w) << 16);
        wb4[t] = p;
    }
}

// ---- Kernel B: fp8 gather + self->LDS + single-barrier W-in-regs MFMA GEMM ----
// 8 waves; wave w: gathers nodes [w*8, w*8+8), computes cols [w*16, w*16+16)
// for all 64 nodes. B-fragments live in registers (8 x bf16x8 = wave's 16-col
// W slice); exactly ONE __syncthreads between gather and GEMM.
__global__ __launch_bounds__(NTHREADS, 6)
void sage_fp8r(const unsigned char* __restrict__ xq,
               const unsigned short* __restrict__ xbs,
               const unsigned short* __restrict__ wb,
               const int* __restrict__ rp,
               const int* __restrict__ ci,
               const float* __restrict__ lb,
               const float* __restrict__ bb,
               float* __restrict__ y,
               int n_out)
{
    __shared__ unsigned short aggS[NT][AGM_LD];  // bf16 self half
    __shared__ unsigned short aggM[NT][AGM_LD];  // bf16 mean half
    __shared__ int rpls[NT + 1];
    __shared__ int cils[NT * 16];

    const int tid   = threadIdx.x;
    const int wave  = tid >> 6;                  // 0..7
    const int lane  = tid & 63;
    const int node0 = blockIdx.x * NT;
    const int nt_act = min(NT, n_out - node0);

    if (tid <= nt_act) rpls[tid] = rp[node0 + tid];
    __syncthreads();
    const int e_base = rpls[0];
    const int e_cnt  = rpls[nt_act] - e_base;
    const bool fits  = (e_cnt <= NT * 16);
    if (fits) {
        for (int i = tid; i < e_cnt; i += NTHREADS) cils[i] = ci[e_base + i];
    }
    __syncthreads();

    // ---- Phase 1: gather. Half-wave split: nsel picks node of the pair;
    //      each lane owns 4 dims -> 16 independent 4B loads per pair. ----
    const int nsel = lane >> 5;
    const int dg4  = (lane & 31) * 4;            // dim base (0,4,...,124)

    for (int p = 0; p < 4; ++p) {
        const int n0 = wave * 8 + p * 2;
        if (n0 >= nt_act) break;
        const bool has1 = (n0 + 1 < nt_act);

        const int s0 = rpls[n0] - e_base;
        const int d0 = rpls[n0 + 1] - e_base - s0;
        int s1 = s0, d1 = d0;
        if (has1) { s1 = rpls[n0 + 1] - e_base; d1 = rpls[n0 + 2] - e_base - s1; }

        const int  my_n   = n0 + nsel;
        const int  my_s   = nsel ? s1 : s0;
        const int  my_d   = nsel ? d1 : d0;
        const bool active = (nsel == 0) || has1;

        // self row copy: 32 lanes x 8B = full 256B bf16 row, coalesced
        if (active) {
            const uint2 sv = *reinterpret_cast<const uint2*>(
                &xbs[(size_t)(node0 + my_n) * D + dg4]);
            *reinterpret_cast<uint2*>(&aggS[my_n][dg4]) = sv;
        }

        f32x2 a01 = (f32x2){0.f, 0.f};
        f32x2 a23 = (f32x2){0.f, 0.f};
        if (fits && has1 && d0 == 16 && d1 == 16) {
            int idx[16];
            #pragma unroll
            for (int u = 0; u < 16; ++u) idx[u] = cils[my_s + u];
            #pragma unroll
            for (int u = 0; u < 16; ++u) {
                const unsigned int v = *reinterpret_cast<const unsigned int*>(
                    &xq[(size_t)idx[u] * D + dg4]);
                a01 += unpack_fp8_lo(v);         // v_pk_add_f32
                a23 += unpack_fp8_hi(v);
            }
        } else if (active) {
            for (int u = 0; u < my_d; ++u) {
                const int c = fits ? cils[my_s + u] : ci[e_base + my_s + u];
                const unsigned int v = *reinterpret_cast<const unsigned int*>(
                    &xq[(size_t)c * D + dg4]);
                a01 += unpack_fp8_lo(v);
                a23 += unpack_fp8_hi(v);
            }
        }
        if (active) {
            const float inv = 1.0f / (float)max(my_d, 1);
            uint2 pk;
            pk.x = (unsigned int)f2bf(a01[0] * inv) | ((unsigned int)f2bf(a01[1] * inv) << 16);
            pk.y = (unsigned int)f2bf(a23[0] * inv) | ((unsigned int)f2bf(a23[1] * inv) << 16);
            *reinterpret_cast<uint2*>(&aggM[my_n][dg4]) = pk;   // 8B, bank-clean
        }
    }

    // ---- B fragments into registers: wave's 16-col slice of W^T, K=256 ----
    const int n15  = lane & 15;
    const int g    = lane >> 4;
    const int colb = wave * 16;

    bf16x8 Bf[8];
    #pragma unroll
    for (int kc = 0; kc < 8; ++kc)
        Bf[kc] = *reinterpret_cast<const bf16x8*>(
            &wb[(size_t)(colb + n15) * K2 + kc * 32 + g * 8]);

    __syncthreads();   // the ONLY barrier: publish aggS/aggM across waves

    // ---- Phase 2: MFMA GEMM, barrier-free. M=64 x N=16 x K=256 per wave ----
    f32x4 acc[4];
    #pragma unroll
    for (int mt = 0; mt < 4; ++mt) acc[mt] = (f32x4){0.f, 0.f, 0.f, 0.f};

    #pragma unroll
    for (int mt = 0; mt < 4; ++mt) {
        const int arow = mt * 16 + n15;
        #pragma unroll
        for (int kc = 0; kc < 8; ++kc) {
            const bf16x8 a = (kc < 4)
                ? *reinterpret_cast<const bf16x8*>(&aggS[arow][kc * 32 + g * 8])
                : *reinterpret_cast<const bf16x8*>(&aggM[arow][(kc - 4) * 32 + g * 8]);
            acc[mt] = __builtin_amdgcn_mfma_f32_16x16x32_bf16(a, Bf[kc], acc[mt], 0, 0, 0);
        }
    }

    // ---- Epilogue: D layout col = lane&15, row = (lane>>4)*4 + reg ----
    const int col = colb + n15;
    const float bs = lb[col] + bb[col];
    #pragma unroll
    for (int mt = 0; mt < 4; ++mt) {
        #pragma unroll
        for (int r = 0; r < 4; ++r) {
            const int row = node0 + mt * 16 + g * 4 + r;
            if (row < n_out)
                y[(size_t)row * D + col] = acc[mt][r] + bs;
        }
    }
}

// --------- Fallback (fp32 gather, barriered) if ws too small ---------
#define AGG_LDF 264
__global__ __launch_bounds__(256, 3)
void sage_fused3(const float* __restrict__ x,
                 const int* __restrict__ rp,
                 const int* __restrict__ ci,
                 const float* __restrict__ W,
                 const float* __restrict__ lb,
                 const float* __restrict__ bb,
                 float* __restrict__ y,
                 int n_out)
{
    __shared__ unsigned short aggB[NT][AGG_LDF];
    __shared__ unsigned short wtTF[D][32];
    __shared__ int rplsF[NT + 1];
    __shared__ int cilsF[NT * 16];

    const int tid   = threadIdx.x;
    const int wave  = tid >> 6;
    const int lane  = tid & 63;
    const int node0 = blockIdx.x * NT;
    const int nt_act = min(NT, n_out - node0);

    if (tid <= nt_act) rplsF[tid] = rp[node0 + tid];
    __syncthreads();
    const int e_base = rplsF[0];
    const int e_cnt  = rplsF[nt_act] - e_base;
    const bool fits  = (e_cnt <= NT * 16);
    if (fits) {
        for (int i = tid; i < e_cnt; i += 256) cilsF[i] = ci[e_base + i];
    }
    __syncthreads();

    for (int t = 0; t < 16; ++t) {
        const int nn = wave * 16 + t;
        if (nn >= nt_act) break;
        const int node = node0 + nn;
        const float2 self =
            *reinterpret_cast<const float2*>(&x[(size_t)node * D + lane * 2]);
        const int s  = rplsF[nn] - e_base;
        const int dg = rplsF[nn + 1] - e_base - s;
        float ax = 0.f, ay = 0.f;
        for (int u = 0; u < dg; ++u) {
            const int c = fits ? cilsF[s + u] : ci[e_base + s + u];
            const float2 v = *reinterpret_cast<const float2*>(
                &x[(size_t)c * D + lane * 2]);
            ax += v.x; ay += v.y;
        }
        const float inv = 1.0f / (float)max(dg, 1);
        *reinterpret_cast<unsigned int*>(&aggB[nn][lane * 2]) =
            (unsigned int)f2bf(self.x) | ((unsigned int)f2bf(self.y) << 16);
        *reinterpret_cast<unsigned int*>(&aggB[nn][D + lane * 2]) =
            (unsigned int)f2bf(ax * inv) | ((unsigned int)f2bf(ay * inv) << 16);
    }

    const int n15 = lane & 15;
    const int g   = lane >> 4;
    f32x4 acc[8];
    #pragma unroll
    for (int f = 0; f < 8; ++f) acc[f] = (f32x4){0.f, 0.f, 0.f, 0.f};

    for (int k0 = 0; k0 < K2; k0 += 32) {
        #pragma unroll
        for (int j = 0; j < 4; ++j) {
            const int idx = j * 256 + tid;
            const int o   = idx >> 3;
            const int c   = idx & 7;
            const float4 w = *reinterpret_cast<const float4*>(
                &W[(size_t)o * K2 + k0 + c * 4]);
            const unsigned int lo = (unsigned int)f2bf(w.x) | ((unsigned int)f2bf(w.y) << 16);
            const unsigned int hi = (unsigned int)f2bf(w.z) | ((unsigned int)f2bf(w.w) << 16);
            *reinterpret_cast<uint2*>(&wtTF[o][c * 4]) = make_uint2(lo, hi);
        }
        __syncthreads();
        const bf16x8 a = *reinterpret_cast<const bf16x8*>(
            &aggB[wave * 16 + n15][k0 + g * 8]);
        #pragma unroll
        for (int f = 0; f < 8; ++f) {
            const bf16x8 b = *reinterpret_cast<const bf16x8*>(&wtTF[f * 16 + n15][g * 8]);
            acc[f] = __builtin_amdgcn_mfma_f32_16x16x32_bf16(a, b, acc[f], 0, 0, 0);
        }
        __syncthreads();
    }

    const int mbase = node0 + wave * 16 + g * 4;
    #pragma unroll
    for (int f = 0; f < 8; ++f) {
        const int col  = f * 16 + n15;
        const float bs = lb[col] + bb[col];
        #pragma unroll
        for (int r = 0; r < 4; ++r) {
            const int row = mbase + r;
            if (row < n_out)
                y[(size_t)row * D + col] = acc[f][r] + bs;
        }
    }
}

extern "C" void kernel_launch(void* const* d_in, const int* in_sizes, int n_in,
                              void* d_out, int out_size, void* d_ws, size_t ws_size,
                              hipStream_t stream)
{
    const float* x  = (const float*)d_in[0];
    const int*   rp = (const int*)d_in[1];
    const int*   ci = (const int*)d_in[2];
    // d_in[3] = sample_count (scalar) — degree comes from row_ptr
    const float* W  = (const float*)d_in[4];
    const float* lb = (const float*)d_in[5];
    const float* bb = (const float*)d_in[6];
    float* y = (float*)d_out;

    const int n_out = in_sizes[1] - 1;
    const int grid  = (n_out + NT - 1) / NT;

    const size_t n_x = (size_t)in_sizes[0];
    const size_t n_w = (size_t)in_sizes[4];
    const size_t xq_bytes  = n_x;                         // fp8: 1 B/elem
    const size_t xbs_bytes = (size_t)n_out * D * 2;       // bf16 self rows
    const size_t wb_bytes  = n_w * 2;
    const size_t need = xq_bytes + xbs_bytes + wb_bytes;

    if (ws_size >= need) {
        unsigned char*  xq  = (unsigned char*)d_ws;
        unsigned short* xbs = (unsigned short*)((char*)d_ws + xq_bytes);
        unsigned short* wb  = (unsigned short*)((char*)d_ws + xq_bytes + xbs_bytes);
        hipLaunchKernelGGL(convert_all, dim3(2048), dim3(256), 0, stream,
                           x, W, (unsigned int*)xq, (uint2*)xbs, (uint2*)wb,
                           (long)(n_x >> 2), (long)(((size_t)n_out * D) >> 2),
                           (long)(n_w >> 2));
        hipLaunchKernelGGL(sage_fp8r, dim3(grid), dim3(NTHREADS), 0, stream,
                           xq, xbs, wb, rp, ci, lb, bb, y, n_out);
    } else {
        hipLaunchKernelGGL(sage_fused3, dim3(grid), dim3(256), 0, stream,
                           x, rp, ci, W, lb, bb, y, n_out);
    }
}